// Round 2
// baseline (1090.538 us; speedup 1.0000x reference)
//
#include <hip/hip_runtime.h>

#define D_MODEL 1024
#define SEQ_L   2048
#define BATCH   4
#define NSTATE  64

// ---------------- fused stacked GEMM: [Delta; Bm; Cm] @ u ----------------
// Row space M = 1152: rows 0..1023 -> delta_ws[b][m][t]
//                     rows 1024..1087 -> Bu_ws[b][t][n]  (transposed store)
//                     rows 1088..1151 -> Cu_ws[b][t][n]
// K = 1024 (d), N = 2048 (t), per batch b.
#define BM 128
#define BN 128
#define BK 32

__global__ __launch_bounds__(256)
void fused_gemm(const float* __restrict__ Wd,   // Delta 1024x1024
                const float* __restrict__ Wb,   // Bm    64x1024
                const float* __restrict__ Wc,   // Cm    64x1024
                const float* __restrict__ u,    // 4x1024x2048
                float* __restrict__ delta_ws,   // 4x1024x2048
                float* __restrict__ Bu_ws,      // 4x2048x64
                float* __restrict__ Cu_ws)      // 4x2048x64
{
    __shared__ float As[BK][BM + 4];   // [k][m], pad to break staging conflicts
    __shared__ float Bs[BK][BN];       // [k][t]

    const int tid = threadIdx.x;
    const int tt  = blockIdx.x;        // t tile 0..15
    const int mt  = blockIdx.y;        // m tile 0..8
    const int b   = blockIdx.z;

    const int t0 = tt * BN;
    const int m0 = mt * BM;

    const int wv  = tid >> 6;          // wave 0..3
    const int ln  = tid & 63;
    const int tm  = ln & 15;           // t-dim thread coord
    const int tmm = ln >> 4;           // m-dim thread coord (0..3)

    float acc[8][8];
#pragma unroll
    for (int i = 0; i < 8; ++i)
#pragma unroll
        for (int j = 0; j < 8; ++j) acc[i][j] = 0.f;

    const int arow_off = tid >> 3;     // 0..31 (row within 32-row group)
    const int akq = (tid & 7) * 4;     // k quad start

    const float* ub = u + (size_t)b * D_MODEL * SEQ_L;

    for (int k0 = 0; k0 < D_MODEL; k0 += BK) {
        // ---- stage A tile: 128 rows x 32 k, stored transposed As[k][m]
#pragma unroll
        for (int r = 0; r < 4; ++r) {
            int lrow = r * 32 + arow_off;
            int grow = m0 + lrow;
            const float* ap;
            if (grow < 1024)      ap = Wd + (size_t)grow * D_MODEL;
            else if (grow < 1088) ap = Wb + (size_t)(grow - 1024) * D_MODEL;
            else                  ap = Wc + (size_t)(grow - 1088) * D_MODEL;
            float4 av = *(const float4*)(ap + k0 + akq);
            As[akq + 0][lrow] = av.x;
            As[akq + 1][lrow] = av.y;
            As[akq + 2][lrow] = av.z;
            As[akq + 3][lrow] = av.w;
        }
        // ---- stage B tile: 32 k x 128 t
#pragma unroll
        for (int r = 0; r < 4; ++r) {
            int kk  = r * 8 + (tid >> 5);
            int col = (tid & 31) * 4;
            float4 bv = *(const float4*)(ub + (size_t)(k0 + kk) * SEQ_L + t0 + col);
            *(float4*)&Bs[kk][col] = bv;
        }
        __syncthreads();

#pragma unroll
        for (int kk = 0; kk < BK; ++kk) {
            float4 a0 = *(const float4*)&As[kk][wv * 32 + tmm * 4];
            float4 a1 = *(const float4*)&As[kk][wv * 32 + tmm * 4 + 16];
            float4 b0 = *(const float4*)&Bs[kk][tm * 4];
            float4 b1 = *(const float4*)&Bs[kk][tm * 4 + 64];
            float am[8] = {a0.x, a0.y, a0.z, a0.w, a1.x, a1.y, a1.z, a1.w};
            float bt[8] = {b0.x, b0.y, b0.z, b0.w, b1.x, b1.y, b1.z, b1.w};
#pragma unroll
            for (int i = 0; i < 8; ++i)
#pragma unroll
                for (int j = 0; j < 8; ++j)
                    acc[i][j] = fmaf(am[i], bt[j], acc[i][j]);
        }
        __syncthreads();
    }

    // ---- epilogue
    if (mt < 8) {
        float* cb = delta_ws + (size_t)b * D_MODEL * SEQ_L;
#pragma unroll
        for (int i = 0; i < 8; ++i) {
            int m = m0 + wv * 32 + tmm * 4 + (i & 3) + (i >> 2) * 16;
            float* crow = cb + (size_t)m * SEQ_L + t0;
            float4 v0 = make_float4(acc[i][0], acc[i][1], acc[i][2], acc[i][3]);
            float4 v1 = make_float4(acc[i][4], acc[i][5], acc[i][6], acc[i][7]);
            *(float4*)(crow + tm * 4) = v0;
            *(float4*)(crow + 64 + tm * 4) = v1;
        }
    } else {
        // rows 1024..1151: Bu / Cu, store transposed as [b][t][n]
#pragma unroll
        for (int i = 0; i < 8; ++i) {
            int rr = wv * 32 + tmm * 4 + (i & 3) + (i >> 2) * 16;  // 0..127
            float* base = (rr < 64 ? Bu_ws : Cu_ws) + (size_t)b * SEQ_L * NSTATE;
            int n = rr & 63;
#pragma unroll
            for (int j = 0; j < 8; ++j) {
                int t = t0 + tm * 4 + (j & 3) + (j >> 2) * 64;
                base[(size_t)t * NSTATE + n] = acc[i][j];
            }
        }
    }
}

// ---------------- scan: one wave per (b,d), lane = n ----------------
// h_n(t) = (delta*A_n) h_n(t-1) + (delta*u) Bu_n(t);  y(t) = sum_n Cu_n(t) h_n(t)
// Shared-memory-free: per-timestep butterfly reduction via __shfl_xor
// (ds_bpermute), predicated lane-capture, coalesced store every 64 t.
__global__ __launch_bounds__(128)
void scan_kernel(const float* __restrict__ delta_ws,
                 const float* __restrict__ u,
                 const float* __restrict__ Bu_ws,
                 const float* __restrict__ Cu_ws,
                 const float* __restrict__ Av,
                 const float* __restrict__ Dv,
                 float* __restrict__ out)
{
    const int wv = threadIdx.x >> 6;
    const int ln = threadIdx.x & 63;
    const int gid = blockIdx.x * 2 + wv;
    const int b = gid >> 10;
    const int d = gid & 1023;

    const float aA = Av[ln];
    const float Dd = Dv[d];
    const size_t row = (size_t)(b * D_MODEL + d) * SEQ_L;
    const float* dp  = delta_ws + row;
    const float* up  = u + row;
    const float* bub = Bu_ws + (size_t)b * SEQ_L * NSTATE + ln;
    const float* cub = Cu_ws + (size_t)b * SEQ_L * NSTATE + ln;
    float* yp = out + row;

    float h = 0.f;
    for (int t0 = 0; t0 < SEQ_L; t0 += 64) {
        // cooperative chunk load: lane i holds values for t = t0+i
        float dreg  = dp[t0 + ln];
        float ureg  = up[t0 + ln];
        float dureg = dreg * ureg;
        const float* bu = bub + (size_t)t0 * NSTATE;
        const float* cu = cub + (size_t)t0 * NSTATE;
        float yacc = 0.f;
#pragma unroll 8
        for (int i = 0; i < 64; ++i) {
            float dl  = __shfl(dreg, i);    // delta(t0+i), broadcast
            float dul = __shfl(dureg, i);   // delta*u at t0+i
            float bv = bu[(size_t)i * NSTATE];   // lane n reads Bu[b][t][n], coalesced
            float cv = cu[(size_t)i * NSTATE];
            h = fmaf(dl * aA, h, dul * bv);
            float ps = cv * h;
            ps += __shfl_xor(ps, 1);
            ps += __shfl_xor(ps, 2);
            ps += __shfl_xor(ps, 4);
            ps += __shfl_xor(ps, 8);
            ps += __shfl_xor(ps, 16);
            ps += __shfl_xor(ps, 32);
            yacc = (ln == i) ? ps : yacc;   // lane i keeps y(t0+i)
        }
        yp[t0 + ln] = yacc + Dd * ureg;     // + u*D skip connection
    }
}

extern "C" void kernel_launch(void* const* d_in, const int* in_sizes, int n_in,
                              void* d_out, int out_size, void* d_ws, size_t ws_size,
                              hipStream_t stream) {
    // setup_inputs order: L, u, A, Bm, Cm, D, Delta
    const float* u  = (const float*)d_in[1];
    const float* A  = (const float*)d_in[2];
    const float* Bm = (const float*)d_in[3];
    const float* Cm = (const float*)d_in[4];
    const float* Dv = (const float*)d_in[5];
    const float* Wd = (const float*)d_in[6];
    float* out = (float*)d_out;

    float* delta_ws = (float*)d_ws;                                   // 32 MB
    float* Bu_ws = delta_ws + (size_t)BATCH * D_MODEL * SEQ_L;        // 2 MB
    float* Cu_ws = Bu_ws + (size_t)BATCH * SEQ_L * NSTATE;            // 2 MB

    dim3 g1(SEQ_L / BN, 9, BATCH);   // 16 x 9 x 4 = 576 blocks
    fused_gemm<<<g1, 256, 0, stream>>>(Wd, Bm, Cm, u, delta_ws, Bu_ws, Cu_ws);

    scan_kernel<<<BATCH * D_MODEL / 2, 128, 0, stream>>>(
        delta_ws, u, Bu_ws, Cu_ws, A, Dv, out);
}

// Round 5
// 643.998 us; speedup vs baseline: 1.6934x; 1.6934x over previous
//
#include <hip/hip_runtime.h>

#define D_MODEL 1024
#define SEQ_L   2048
#define BATCH   4
#define NSTATE  64

// ---------------- fused stacked GEMM: [Delta; Bm; Cm] @ u ----------------
// Row space M = 1152: rows 0..1023 -> delta_ws[b][m][t]
//                     rows 1024..1151 -> BCu_ws[b][t][2n+{0=Bu,1=Cu}]
#define BM 128
#define BN 128
#define BK 32

__global__ __launch_bounds__(256)
void fused_gemm(const float* __restrict__ Wd,   // Delta 1024x1024
                const float* __restrict__ Wb,   // Bm    64x1024
                const float* __restrict__ Wc,   // Cm    64x1024
                const float* __restrict__ u,    // 4x1024x2048
                float* __restrict__ delta_ws,   // 4x1024x2048
                float* __restrict__ BCu_ws)     // 4x2048x128 interleaved
{
    __shared__ float As[BK][BM + 4];   // [k][m]
    __shared__ float Bs[BK][BN];       // [k][t]

    const int tid = threadIdx.x;
    const int tt  = blockIdx.x;
    const int mt  = blockIdx.y;
    const int b   = blockIdx.z;

    const int t0 = tt * BN;
    const int m0 = mt * BM;

    const int wv  = tid >> 6;
    const int ln  = tid & 63;
    const int tm  = ln & 15;
    const int tmm = ln >> 4;

    float acc[8][8];
#pragma unroll
    for (int i = 0; i < 8; ++i)
#pragma unroll
        for (int j = 0; j < 8; ++j) acc[i][j] = 0.f;

    const int arow_off = tid >> 3;
    const int akq = (tid & 7) * 4;

    const float* ub = u + (size_t)b * D_MODEL * SEQ_L;

    for (int k0 = 0; k0 < D_MODEL; k0 += BK) {
#pragma unroll
        for (int r = 0; r < 4; ++r) {
            int lrow = r * 32 + arow_off;
            int grow = m0 + lrow;
            const float* ap;
            if (grow < 1024)      ap = Wd + (size_t)grow * D_MODEL;
            else if (grow < 1088) ap = Wb + (size_t)(grow - 1024) * D_MODEL;
            else                  ap = Wc + (size_t)(grow - 1088) * D_MODEL;
            float4 av = *(const float4*)(ap + k0 + akq);
            As[akq + 0][lrow] = av.x;
            As[akq + 1][lrow] = av.y;
            As[akq + 2][lrow] = av.z;
            As[akq + 3][lrow] = av.w;
        }
#pragma unroll
        for (int r = 0; r < 4; ++r) {
            int kk  = r * 8 + (tid >> 5);
            int col = (tid & 31) * 4;
            float4 bv = *(const float4*)(ub + (size_t)(k0 + kk) * SEQ_L + t0 + col);
            *(float4*)&Bs[kk][col] = bv;
        }
        __syncthreads();

#pragma unroll
        for (int kk = 0; kk < BK; ++kk) {
            float4 a0 = *(const float4*)&As[kk][wv * 32 + tmm * 4];
            float4 a1 = *(const float4*)&As[kk][wv * 32 + tmm * 4 + 16];
            float4 b0 = *(const float4*)&Bs[kk][tm * 4];
            float4 b1 = *(const float4*)&Bs[kk][tm * 4 + 64];
            float am[8] = {a0.x, a0.y, a0.z, a0.w, a1.x, a1.y, a1.z, a1.w};
            float bt[8] = {b0.x, b0.y, b0.z, b0.w, b1.x, b1.y, b1.z, b1.w};
#pragma unroll
            for (int i = 0; i < 8; ++i)
#pragma unroll
                for (int j = 0; j < 8; ++j)
                    acc[i][j] = fmaf(am[i], bt[j], acc[i][j]);
        }
        __syncthreads();
    }

    if (mt < 8) {
        float* cb = delta_ws + (size_t)b * D_MODEL * SEQ_L;
#pragma unroll
        for (int i = 0; i < 8; ++i) {
            int m = m0 + wv * 32 + tmm * 4 + (i & 3) + (i >> 2) * 16;
            float* crow = cb + (size_t)m * SEQ_L + t0;
            float4 v0 = make_float4(acc[i][0], acc[i][1], acc[i][2], acc[i][3]);
            float4 v1 = make_float4(acc[i][4], acc[i][5], acc[i][6], acc[i][7]);
            *(float4*)(crow + tm * 4) = v0;
            *(float4*)(crow + 64 + tm * 4) = v1;
        }
    } else {
        // rows 1024..1151: Bu / Cu, interleaved store BCu[b][t][2n+off]
        float* base = BCu_ws + (size_t)b * SEQ_L * 2 * NSTATE;
#pragma unroll
        for (int i = 0; i < 8; ++i) {
            int rr = wv * 32 + tmm * 4 + (i & 3) + (i >> 2) * 16;  // 0..127
            int n   = rr & 63;
            int off = (rr < 64) ? 0 : 1;   // 0=Bu, 1=Cu
#pragma unroll
            for (int j = 0; j < 8; ++j) {
                int t = t0 + tm * 4 + (j & 3) + (j >> 2) * 64;
                base[(size_t)t * 128 + 2 * n + off] = acc[i][j];
            }
        }
    }
}

// ---------------- scan: one wave per (b,d), lane = n ----------------
// Broadcasts via v_readlane (VALU); y-reduction via barrier-protected
// LDS transpose (1 conflict-free b32 write/t, b64 strided reads).
__global__ __launch_bounds__(128)
void scan_kernel(const float* __restrict__ delta_ws,
                 const float* __restrict__ u,
                 const float* __restrict__ BCu,   // [b][t][2n+{0,1}]
                 const float* __restrict__ Av,
                 const float* __restrict__ Dv,
                 float* __restrict__ out)
{
    __shared__ float red[2][64][66];   // [wave][t-in-chunk][n], stride 66
    const int wv = threadIdx.x >> 6;
    const int ln = threadIdx.x & 63;
    const int gid = blockIdx.x * 2 + wv;
    const int b = gid >> 10;
    const int d = gid & 1023;

    const float aA = Av[ln];
    const float Dd = Dv[d];
    const size_t row = (size_t)(b * D_MODEL + d) * SEQ_L;
    const float* dp = delta_ws + row;
    const float* up = u + row;
    const float* bc = BCu + (size_t)b * SEQ_L * 2 * NSTATE + 2 * ln;
    float* yp = out + row;

    float h = 0.f;
    for (int t0 = 0; t0 < SEQ_L; t0 += 64) {
        // lane i holds delta/u for t = t0+i
        float dreg  = dp[t0 + ln];
        float ureg  = up[t0 + ln];
        float dureg = dreg * ureg;
        const float* bcc = bc + (size_t)t0 * 128;
#pragma unroll
        for (int i = 0; i < 64; ++i) {
            float dl  = __int_as_float(__builtin_amdgcn_readlane(__float_as_int(dreg),  i));
            float dul = __int_as_float(__builtin_amdgcn_readlane(__float_as_int(dureg), i));
            float2 v = *(const float2*)(bcc + (size_t)i * 128);   // {Bu, Cu}, coalesced
            h = fmaf(dl * aA, h, dul * v.x);
            red[wv][i][ln] = v.y * h;
        }
        __syncthreads();   // drain writes before transpose reads (r1 bug fix)
        float acc0 = 0.f, acc1 = 0.f;
#pragma unroll
        for (int nn = 0; nn < 32; ++nn) {
            float2 pr = *(const float2*)&red[wv][ln][2 * nn];   // row ln = time t0+ln
            acc0 += pr.x; acc1 += pr.y;
        }
        yp[t0 + ln] = acc0 + acc1 + Dd * ureg;
        __syncthreads();   // protect WAR against next chunk's writes
    }
}

extern "C" void kernel_launch(void* const* d_in, const int* in_sizes, int n_in,
                              void* d_out, int out_size, void* d_ws, size_t ws_size,
                              hipStream_t stream) {
    // setup_inputs order: L, u, A, Bm, Cm, D, Delta
    const float* u  = (const float*)d_in[1];
    const float* A  = (const float*)d_in[2];
    const float* Bm = (const float*)d_in[3];
    const float* Cm = (const float*)d_in[4];
    const float* Dv = (const float*)d_in[5];
    const float* Wd = (const float*)d_in[6];
    float* out = (float*)d_out;

    float* delta_ws = (float*)d_ws;                                   // 32 MB
    float* BCu_ws = delta_ws + (size_t)BATCH * D_MODEL * SEQ_L;       // 4 MB

    dim3 g1(SEQ_L / BN, 9, BATCH);   // 16 x 9 x 4 = 576 blocks
    fused_gemm<<<g1, 256, 0, stream>>>(Wd, Bm, Cm, u, delta_ws, BCu_ws);

    scan_kernel<<<BATCH * D_MODEL / 2, 128, 0, stream>>>(
        delta_ws, u, BCu_ws, A, Dv, out);
}

// Round 6
// 505.666 us; speedup vs baseline: 2.1566x; 1.2736x over previous
//
#include <hip/hip_runtime.h>

#define D_MODEL 1024
#define SEQ_L   2048
#define BATCH   4
#define NSTATE  64

typedef __bf16 bf16x8 __attribute__((ext_vector_type(8)));
typedef float  f32x4  __attribute__((ext_vector_type(4)));

static __device__ inline unsigned short bf16_rn(float x) {
    unsigned u = __float_as_uint(x);
    u += 0x7fff + ((u >> 16) & 1);
    return (unsigned short)(u >> 16);
}
static __device__ inline float bf16_to_f32(unsigned short h) {
    return __uint_as_float((unsigned)h << 16);
}
static __device__ inline bf16x8 ld_frag(const unsigned char* p) {
    union { uint4 u; bf16x8 b; } c;
    c.u = *(const uint4*)p;
    return c.b;
}

// ---------------- bf16-split MFMA GEMM: [Delta; Bm; Cm] @ u ----------------
// D = W*U via Whi*Uhi + Whi*Ulo + Wlo*Uhi (fp32 MFMA accum).
// Rows 0..1023 -> delta_ws[b][m][t]; rows 1024..1151 -> BCu[b][t][2n+{0,1}]
// Tiles: BM=128(m) x BN=128(t) x BK=32(k). 256 thr = 4 waves (2x2 of 64x64).
#define AROWB 80   // LDS row stride bytes: 32 bf16 = 64B + 16B pad (2-way reads)

__global__ __launch_bounds__(256)
void fused_gemm(const float* __restrict__ Wd,   // Delta 1024x1024
                const float* __restrict__ Wb,   // Bm    64x1024
                const float* __restrict__ Wc,   // Cm    64x1024
                const float* __restrict__ u,    // 4x1024x2048 fp32
                float* __restrict__ delta_ws,   // 4x1024x2048
                float* __restrict__ BCu_ws)     // 4x2048x128 interleaved
{
    __shared__ __align__(16) unsigned char lds[4 * 128 * AROWB];
    unsigned char* As_hi = lds;
    unsigned char* As_lo = lds + 128 * AROWB;
    unsigned char* Bs_hi = lds + 2 * 128 * AROWB;
    unsigned char* Bs_lo = lds + 3 * 128 * AROWB;

    const int tid = threadIdx.x;
    const int t0  = blockIdx.x * 128;
    const int mt  = blockIdx.y;
    const int m0  = mt * 128;
    const int b   = blockIdx.z;

    const int wv = tid >> 6;
    const int ln = tid & 63;
    const int wr = wv >> 1;         // wave row (0/1) -> 64 m
    const int wc = wv & 1;          // wave col (0/1) -> 64 t
    const int l15 = ln & 15;
    const int l4  = ln >> 4;        // 0..3

    // staging coords
    const int arow = tid >> 3;          // 0..31
    const int akq  = (tid & 7) * 4;     // k quad
    const int bt   = tid & 127;         // t within tile
    const int bkh  = (tid >> 7) * 16;   // k half: 0 or 16

    const float* ub = u + (size_t)b * D_MODEL * SEQ_L;

    f32x4 acc[4][4];
#pragma unroll
    for (int i = 0; i < 4; ++i)
#pragma unroll
        for (int j = 0; j < 4; ++j) acc[i][j] = (f32x4){0.f, 0.f, 0.f, 0.f};

    for (int k0 = 0; k0 < D_MODEL; k0 += 32) {
        // ---- stage A (W rows, [m][k] bf16 hi/lo) ----
#pragma unroll
        for (int r = 0; r < 4; ++r) {
            int lrow = r * 32 + arow;
            int grow = m0 + lrow;
            const float* ap;
            if (grow < 1024)      ap = Wd + (size_t)grow * D_MODEL;
            else if (grow < 1088) ap = Wb + (size_t)(grow - 1024) * D_MODEL;
            else                  ap = Wc + (size_t)(grow - 1088) * D_MODEL;
            float4 av = *(const float4*)(ap + k0 + akq);
            unsigned short h0 = bf16_rn(av.x), h1 = bf16_rn(av.y),
                           h2 = bf16_rn(av.z), h3 = bf16_rn(av.w);
            unsigned short g0 = bf16_rn(av.x - bf16_to_f32(h0)),
                           g1 = bf16_rn(av.y - bf16_to_f32(h1)),
                           g2 = bf16_rn(av.z - bf16_to_f32(h2)),
                           g3 = bf16_rn(av.w - bf16_to_f32(h3));
            uint2 hp = make_uint2((unsigned)h0 | ((unsigned)h1 << 16),
                                  (unsigned)h2 | ((unsigned)h3 << 16));
            uint2 lp = make_uint2((unsigned)g0 | ((unsigned)g1 << 16),
                                  (unsigned)g2 | ((unsigned)g3 << 16));
            *(uint2*)(As_hi + lrow * AROWB + akq * 2) = hp;
            *(uint2*)(As_lo + lrow * AROWB + akq * 2) = lp;
        }
        // ---- stage B (u, [t][k] bf16 hi/lo; reads lane-coalesced along t) ----
        {
            const float* up0 = ub + (size_t)(k0 + bkh) * SEQ_L + t0 + bt;
            float v[16];
#pragma unroll
            for (int i = 0; i < 16; ++i) v[i] = up0[(size_t)i * SEQ_L];
            unsigned hw[8], lw[8];
#pragma unroll
            for (int i = 0; i < 8; ++i) {
                unsigned short ha = bf16_rn(v[2 * i]), hb = bf16_rn(v[2 * i + 1]);
                unsigned short la = bf16_rn(v[2 * i] - bf16_to_f32(ha));
                unsigned short lb = bf16_rn(v[2 * i + 1] - bf16_to_f32(hb));
                hw[i] = (unsigned)ha | ((unsigned)hb << 16);
                lw[i] = (unsigned)la | ((unsigned)lb << 16);
            }
            unsigned char* ph = Bs_hi + bt * AROWB + bkh * 2;
            unsigned char* pl = Bs_lo + bt * AROWB + bkh * 2;
            *(uint4*)ph        = make_uint4(hw[0], hw[1], hw[2], hw[3]);
            *(uint4*)(ph + 16) = make_uint4(hw[4], hw[5], hw[6], hw[7]);
            *(uint4*)pl        = make_uint4(lw[0], lw[1], lw[2], lw[3]);
            *(uint4*)(pl + 16) = make_uint4(lw[4], lw[5], lw[6], lw[7]);
        }
        __syncthreads();

        // ---- fragments: A[row=l15][k=l4*8+j], B[k=l4*8+j][col=l15] ----
        bf16x8 ah[4], al[4], bh[4], bl[4];
#pragma unroll
        for (int f = 0; f < 4; ++f) {
            int ar = wr * 64 + f * 16 + l15;
            ah[f] = ld_frag(As_hi + ar * AROWB + l4 * 16);
            al[f] = ld_frag(As_lo + ar * AROWB + l4 * 16);
            int br = wc * 64 + f * 16 + l15;
            bh[f] = ld_frag(Bs_hi + br * AROWB + l4 * 16);
            bl[f] = ld_frag(Bs_lo + br * AROWB + l4 * 16);
        }
#pragma unroll
        for (int fm = 0; fm < 4; ++fm)
#pragma unroll
            for (int fn = 0; fn < 4; ++fn) {
                acc[fm][fn] = __builtin_amdgcn_mfma_f32_16x16x32_bf16(
                    ah[fm], bh[fn], acc[fm][fn], 0, 0, 0);
                acc[fm][fn] = __builtin_amdgcn_mfma_f32_16x16x32_bf16(
                    ah[fm], bl[fn], acc[fm][fn], 0, 0, 0);
                acc[fm][fn] = __builtin_amdgcn_mfma_f32_16x16x32_bf16(
                    al[fm], bh[fn], acc[fm][fn], 0, 0, 0);
            }
        __syncthreads();
    }

    // ---- epilogue: D[row=(l>>4)*4+r][col=l&15] ----
    if (mt < 8) {
        float* cb = delta_ws + (size_t)b * D_MODEL * SEQ_L;
#pragma unroll
        for (int fm = 0; fm < 4; ++fm)
#pragma unroll
            for (int fn = 0; fn < 4; ++fn) {
                int t = t0 + wc * 64 + fn * 16 + l15;
#pragma unroll
                for (int r = 0; r < 4; ++r) {
                    int m = m0 + wr * 64 + fm * 16 + l4 * 4 + r;
                    cb[(size_t)m * SEQ_L + t] = acc[fm][fn][r];
                }
            }
    } else {
        float* base = BCu_ws + (size_t)b * SEQ_L * 2 * NSTATE;
#pragma unroll
        for (int fm = 0; fm < 4; ++fm)
#pragma unroll
            for (int fn = 0; fn < 4; ++fn) {
                int t = t0 + wc * 64 + fn * 16 + l15;
#pragma unroll
                for (int r = 0; r < 4; ++r) {
                    int rr = wr * 64 + fm * 16 + l4 * 4 + r;   // 0..127
                    int n = rr & 63, off = rr >> 6;            // 0=Bu, 1=Cu
                    base[(size_t)t * 128 + 2 * n + off] = acc[fm][fn][r];
                }
            }
    }
}

// ---------------- scan: one wave per (b,d), lane = n (UNCHANGED, validated) --
__global__ __launch_bounds__(128)
void scan_kernel(const float* __restrict__ delta_ws,
                 const float* __restrict__ u,
                 const float* __restrict__ BCu,   // [b][t][2n+{0,1}]
                 const float* __restrict__ Av,
                 const float* __restrict__ Dv,
                 float* __restrict__ out)
{
    __shared__ float red[2][64][66];
    const int wv = threadIdx.x >> 6;
    const int ln = threadIdx.x & 63;
    const int gid = blockIdx.x * 2 + wv;
    const int b = gid >> 10;
    const int d = gid & 1023;

    const float aA = Av[ln];
    const float Dd = Dv[d];
    const size_t row = (size_t)(b * D_MODEL + d) * SEQ_L;
    const float* dp = delta_ws + row;
    const float* up = u + row;
    const float* bc = BCu + (size_t)b * SEQ_L * 2 * NSTATE + 2 * ln;
    float* yp = out + row;

    float h = 0.f;
    for (int t0 = 0; t0 < SEQ_L; t0 += 64) {
        float dreg  = dp[t0 + ln];
        float ureg  = up[t0 + ln];
        float dureg = dreg * ureg;
        const float* bcc = bc + (size_t)t0 * 128;
#pragma unroll
        for (int i = 0; i < 64; ++i) {
            float dl  = __int_as_float(__builtin_amdgcn_readlane(__float_as_int(dreg),  i));
            float dul = __int_as_float(__builtin_amdgcn_readlane(__float_as_int(dureg), i));
            float2 v = *(const float2*)(bcc + (size_t)i * 128);
            h = fmaf(dl * aA, h, dul * v.x);
            red[wv][i][ln] = v.y * h;
        }
        __syncthreads();
        float acc0 = 0.f, acc1 = 0.f;
#pragma unroll
        for (int nn = 0; nn < 32; ++nn) {
            float2 pr = *(const float2*)&red[wv][ln][2 * nn];
            acc0 += pr.x; acc1 += pr.y;
        }
        yp[t0 + ln] = acc0 + acc1 + Dd * ureg;
        __syncthreads();
    }
}

extern "C" void kernel_launch(void* const* d_in, const int* in_sizes, int n_in,
                              void* d_out, int out_size, void* d_ws, size_t ws_size,
                              hipStream_t stream) {
    // setup_inputs order: L, u, A, Bm, Cm, D, Delta
    const float* u  = (const float*)d_in[1];
    const float* A  = (const float*)d_in[2];
    const float* Bm = (const float*)d_in[3];
    const float* Cm = (const float*)d_in[4];
    const float* Dv = (const float*)d_in[5];
    const float* Wd = (const float*)d_in[6];
    float* out = (float*)d_out;

    float* delta_ws = (float*)d_ws;                                   // 32 MB
    float* BCu_ws = delta_ws + (size_t)BATCH * D_MODEL * SEQ_L;       // 4 MB

    dim3 g1(SEQ_L / 128, 9, BATCH);   // 16 x 9 x 4 = 576 blocks
    fused_gemm<<<g1, 256, 0, stream>>>(Wd, Bm, Cm, u, delta_ws, BCu_ws);

    scan_kernel<<<BATCH * D_MODEL / 2, 128, 0, stream>>>(
        delta_ws, u, BCu_ws, A, Dv, out);
}

// Round 7
// 470.679 us; speedup vs baseline: 2.3169x; 1.0743x over previous
//
#include <hip/hip_runtime.h>

#define D_MODEL 1024
#define SEQ_L   2048
#define BATCH   4
#define NSTATE  64

typedef __bf16 bf16x8 __attribute__((ext_vector_type(8)));
typedef float  f32x4  __attribute__((ext_vector_type(4)));

static __device__ inline unsigned short bf16_rn(float x) {
    unsigned u = __float_as_uint(x);
    u += 0x7fff + ((u >> 16) & 1);
    return (unsigned short)(u >> 16);
}
static __device__ inline float bf16_to_f32(unsigned short h) {
    return __uint_as_float((unsigned)h << 16);
}
static __device__ inline bf16x8 ld_frag(const unsigned char* p) {
    union { uint4 u; bf16x8 b; } c;
    c.u = *(const uint4*)p;
    return c.b;
}

// ---------------- bf16-split MFMA GEMM: [Delta; Bm; Cm] @ u ----------------
// (UNCHANGED from round 6 — validated)
#define AROWB 80

__global__ __launch_bounds__(256)
void fused_gemm(const float* __restrict__ Wd,   // Delta 1024x1024
                const float* __restrict__ Wb,   // Bm    64x1024
                const float* __restrict__ Wc,   // Cm    64x1024
                const float* __restrict__ u,    // 4x1024x2048 fp32
                float* __restrict__ delta_ws,   // 4x1024x2048
                float* __restrict__ BCu_ws)     // 4x2048x128 interleaved
{
    __shared__ __align__(16) unsigned char lds[4 * 128 * AROWB];
    unsigned char* As_hi = lds;
    unsigned char* As_lo = lds + 128 * AROWB;
    unsigned char* Bs_hi = lds + 2 * 128 * AROWB;
    unsigned char* Bs_lo = lds + 3 * 128 * AROWB;

    const int tid = threadIdx.x;
    const int t0  = blockIdx.x * 128;
    const int mt  = blockIdx.y;
    const int m0  = mt * 128;
    const int b   = blockIdx.z;

    const int wv = tid >> 6;
    const int ln = tid & 63;
    const int wr = wv >> 1;
    const int wc = wv & 1;
    const int l15 = ln & 15;
    const int l4  = ln >> 4;

    const int arow = tid >> 3;
    const int akq  = (tid & 7) * 4;
    const int bt   = tid & 127;
    const int bkh  = (tid >> 7) * 16;

    const float* ub = u + (size_t)b * D_MODEL * SEQ_L;

    f32x4 acc[4][4];
#pragma unroll
    for (int i = 0; i < 4; ++i)
#pragma unroll
        for (int j = 0; j < 4; ++j) acc[i][j] = (f32x4){0.f, 0.f, 0.f, 0.f};

    for (int k0 = 0; k0 < D_MODEL; k0 += 32) {
#pragma unroll
        for (int r = 0; r < 4; ++r) {
            int lrow = r * 32 + arow;
            int grow = m0 + lrow;
            const float* ap;
            if (grow < 1024)      ap = Wd + (size_t)grow * D_MODEL;
            else if (grow < 1088) ap = Wb + (size_t)(grow - 1024) * D_MODEL;
            else                  ap = Wc + (size_t)(grow - 1088) * D_MODEL;
            float4 av = *(const float4*)(ap + k0 + akq);
            unsigned short h0 = bf16_rn(av.x), h1 = bf16_rn(av.y),
                           h2 = bf16_rn(av.z), h3 = bf16_rn(av.w);
            unsigned short g0 = bf16_rn(av.x - bf16_to_f32(h0)),
                           g1 = bf16_rn(av.y - bf16_to_f32(h1)),
                           g2 = bf16_rn(av.z - bf16_to_f32(h2)),
                           g3 = bf16_rn(av.w - bf16_to_f32(h3));
            uint2 hp = make_uint2((unsigned)h0 | ((unsigned)h1 << 16),
                                  (unsigned)h2 | ((unsigned)h3 << 16));
            uint2 lp = make_uint2((unsigned)g0 | ((unsigned)g1 << 16),
                                  (unsigned)g2 | ((unsigned)g3 << 16));
            *(uint2*)(As_hi + lrow * AROWB + akq * 2) = hp;
            *(uint2*)(As_lo + lrow * AROWB + akq * 2) = lp;
        }
        {
            const float* up0 = ub + (size_t)(k0 + bkh) * SEQ_L + t0 + bt;
            float v[16];
#pragma unroll
            for (int i = 0; i < 16; ++i) v[i] = up0[(size_t)i * SEQ_L];
            unsigned hw[8], lw[8];
#pragma unroll
            for (int i = 0; i < 8; ++i) {
                unsigned short ha = bf16_rn(v[2 * i]), hb = bf16_rn(v[2 * i + 1]);
                unsigned short la = bf16_rn(v[2 * i] - bf16_to_f32(ha));
                unsigned short lb = bf16_rn(v[2 * i + 1] - bf16_to_f32(hb));
                hw[i] = (unsigned)ha | ((unsigned)hb << 16);
                lw[i] = (unsigned)la | ((unsigned)lb << 16);
            }
            unsigned char* ph = Bs_hi + bt * AROWB + bkh * 2;
            unsigned char* pl = Bs_lo + bt * AROWB + bkh * 2;
            *(uint4*)ph        = make_uint4(hw[0], hw[1], hw[2], hw[3]);
            *(uint4*)(ph + 16) = make_uint4(hw[4], hw[5], hw[6], hw[7]);
            *(uint4*)pl        = make_uint4(lw[0], lw[1], lw[2], lw[3]);
            *(uint4*)(pl + 16) = make_uint4(lw[4], lw[5], lw[6], lw[7]);
        }
        __syncthreads();

        bf16x8 ah[4], al[4], bh[4], bl[4];
#pragma unroll
        for (int f = 0; f < 4; ++f) {
            int ar = wr * 64 + f * 16 + l15;
            ah[f] = ld_frag(As_hi + ar * AROWB + l4 * 16);
            al[f] = ld_frag(As_lo + ar * AROWB + l4 * 16);
            int br = wc * 64 + f * 16 + l15;
            bh[f] = ld_frag(Bs_hi + br * AROWB + l4 * 16);
            bl[f] = ld_frag(Bs_lo + br * AROWB + l4 * 16);
        }
#pragma unroll
        for (int fm = 0; fm < 4; ++fm)
#pragma unroll
            for (int fn = 0; fn < 4; ++fn) {
                acc[fm][fn] = __builtin_amdgcn_mfma_f32_16x16x32_bf16(
                    ah[fm], bh[fn], acc[fm][fn], 0, 0, 0);
                acc[fm][fn] = __builtin_amdgcn_mfma_f32_16x16x32_bf16(
                    ah[fm], bl[fn], acc[fm][fn], 0, 0, 0);
                acc[fm][fn] = __builtin_amdgcn_mfma_f32_16x16x32_bf16(
                    al[fm], bh[fn], acc[fm][fn], 0, 0, 0);
            }
        __syncthreads();
    }

    if (mt < 8) {
        float* cb = delta_ws + (size_t)b * D_MODEL * SEQ_L;
#pragma unroll
        for (int fm = 0; fm < 4; ++fm)
#pragma unroll
            for (int fn = 0; fn < 4; ++fn) {
                int t = t0 + wc * 64 + fn * 16 + l15;
#pragma unroll
                for (int r = 0; r < 4; ++r) {
                    int m = m0 + wr * 64 + fm * 16 + l4 * 4 + r;
                    cb[(size_t)m * SEQ_L + t] = acc[fm][fn][r];
                }
            }
    } else {
        float* base = BCu_ws + (size_t)b * SEQ_L * 2 * NSTATE;
#pragma unroll
        for (int fm = 0; fm < 4; ++fm)
#pragma unroll
            for (int fn = 0; fn < 4; ++fn) {
                int t = t0 + wc * 64 + fn * 16 + l15;
#pragma unroll
                for (int r = 0; r < 4; ++r) {
                    int rr = wr * 64 + fm * 16 + l4 * 4 + r;
                    int n = rr & 63, off = rr >> 6;
                    base[(size_t)t * 128 + 2 * n + off] = acc[fm][fn][r];
                }
            }
    }
}

// ---------------- scan: ONE wave per (b,d), chunk=32, small LDS ----------------
// h_n(t) = (delta*A_n) h_n(t-1) + (delta*u) Bu_n(t);  y(t) = sum_n Cu_n(t) h_n(t)
// Same validated structure as round 5, resized: 8448 B LDS -> ~18 blocks/CU.
__global__ __launch_bounds__(64)
void scan_kernel(const float* __restrict__ delta_ws,
                 const float* __restrict__ u,
                 const float* __restrict__ BCu,   // [b][t][2n+{0,1}]
                 const float* __restrict__ Av,
                 const float* __restrict__ Dv,
                 float* __restrict__ out)
{
    __shared__ float red[32][66];   // [t-in-chunk][n], stride 66 (0 conflicts, r5)
    const int ln = threadIdx.x;
    const int gid = blockIdx.x;     // one wave per (b,d)
    const int b = gid >> 10;
    const int d = gid & 1023;

    const float aA = Av[ln];
    const float Dd = Dv[d];
    const size_t row = (size_t)(b * D_MODEL + d) * SEQ_L;
    const float* dp = delta_ws + row;
    const float* up = u + row;
    const float* bc = BCu + (size_t)b * SEQ_L * 2 * NSTATE + 2 * ln;
    float* yp = out + row;

    const int tc   = ln & 31;   // t-within-chunk for reduce/store phase
    const int half = ln >> 5;   // n-half for reduce phase

    float h = 0.f;
    for (int t0 = 0; t0 < SEQ_L; t0 += 32) {
        // lanes 0..31 hold delta/u for t = t0+tc (upper half duplicates)
        float dreg  = dp[t0 + tc];
        float ureg  = up[t0 + tc];
        float dureg = dreg * ureg;
        const float* bcc = bc + (size_t)t0 * 128;
#pragma unroll
        for (int i = 0; i < 32; ++i) {
            float dl  = __int_as_float(__builtin_amdgcn_readlane(__float_as_int(dreg),  i));
            float dul = __int_as_float(__builtin_amdgcn_readlane(__float_as_int(dureg), i));
            float2 v = *(const float2*)(bcc + (size_t)i * 128);   // {Bu, Cu}
            h = fmaf(dl * aA, h, dul * v.x);
            red[i][ln] = v.y * h;
        }
        __syncthreads();   // drain LDS writes before transpose reads
        // lane (tc, half) sums n = half*32 .. half*32+31 of row tc
        float s0 = 0.f, s1 = 0.f;
#pragma unroll
        for (int j = 0; j < 16; ++j) {
            float2 pr = *(const float2*)&red[tc][half * 32 + 2 * j];
            s0 += pr.x; s1 += pr.y;
        }
        float s = s0 + s1;
        s += __shfl_xor(s, 32);            // combine n-halves
        if (ln < 32)
            yp[t0 + tc] = s + Dd * ureg;   // + u*D skip (ureg valid for ln<32)
        __syncthreads();   // WAR: next chunk's writes
    }
}

extern "C" void kernel_launch(void* const* d_in, const int* in_sizes, int n_in,
                              void* d_out, int out_size, void* d_ws, size_t ws_size,
                              hipStream_t stream) {
    // setup_inputs order: L, u, A, Bm, Cm, D, Delta
    const float* u  = (const float*)d_in[1];
    const float* A  = (const float*)d_in[2];
    const float* Bm = (const float*)d_in[3];
    const float* Cm = (const float*)d_in[4];
    const float* Dv = (const float*)d_in[5];
    const float* Wd = (const float*)d_in[6];
    float* out = (float*)d_out;

    float* delta_ws = (float*)d_ws;                                   // 32 MB
    float* BCu_ws = delta_ws + (size_t)BATCH * D_MODEL * SEQ_L;       // 4 MB

    dim3 g1(SEQ_L / 128, 9, BATCH);   // 16 x 9 x 4 = 576 blocks
    fused_gemm<<<g1, 256, 0, stream>>>(Wd, Bm, Cm, u, delta_ws, BCu_ws);

    scan_kernel<<<BATCH * D_MODEL, 64, 0, stream>>>(
        delta_ws, u, BCu_ws, A, Dv, out);
}